// Round 3
// baseline (600.597 us; speedup 1.0000x reference)
//
#include <hip/hip_runtime.h>
#include <math.h>

#define SE_B   32
#define SE_C   256
#define SE_HID 16
#define SE_HW  4096   // 64*64
#define SE_HW4 1024   // float4 per (b,c) plane
#define SE_PLANES (SE_B * SE_C)

typedef float f4v __attribute__((ext_vector_type(4)));

// Zero the done-counter (ws is poisoned to 0xAA before every call).
__global__ void se_init_kernel(unsigned int* counter) { *counter = 0u; }

// Kernel 1: per-(b,c) plane mean, one 256-thread block per plane.
// Normal (caching) loads on purpose: leaves x resident in L3 for the scale
// pass. The LAST block to finish (atomic counter) computes all B*C gates.
__global__ __launch_bounds__(256) void se_mean_gate_kernel(
    const float* __restrict__ x,
    const float* __restrict__ w1, const float* __restrict__ b1,
    const float* __restrict__ w2, const float* __restrict__ b2,
    float* __restrict__ s, float* __restrict__ g,
    unsigned int* __restrict__ counter) {
    const int plane = blockIdx.x;  // b*C + c
    const int tid = threadIdx.x;
    const float4* xp = (const float4*)x + (size_t)plane * SE_HW4;

    float sum = 0.f;
#pragma unroll
    for (int k = 0; k < 4; ++k) {
        float4 v = xp[tid + k * 256];
        sum += (v.x + v.y) + (v.z + v.w);
    }
#pragma unroll
    for (int off = 32; off > 0; off >>= 1) sum += __shfl_down(sum, off, 64);

    __shared__ float part[4];
    __shared__ int last_flag;
    if ((tid & 63) == 0) part[tid >> 6] = sum;
    __syncthreads();
    if (tid == 0) {
        s[plane] = ((part[0] + part[1]) + (part[2] + part[3])) * (1.0f / SE_HW);
        __threadfence();                             // release s[plane]
        unsigned int n = atomicAdd(counter, 1u);     // device-scope
        last_flag = (n == SE_PLANES - 1);
    }
    __syncthreads();
    if (!last_flag) return;

    // ---- tail: only the final block executes this ----
    __threadfence();  // acquire: observe every block's s[] store

    // h[b][i] = relu(b1[i] + dot(s[b,:], w1[i,:])) ; 512 values, 2 rounds
    __shared__ float h_sh[SE_B][SE_HID];  // 2 KB
#pragma unroll
    for (int rb = 0; rb < 2; ++rb) {
        const int b = rb * 16 + (tid >> 4);
        const int i = tid & 15;
        const float* srow = s + b * SE_C;
        const float* wrow = w1 + i * SE_C;
        float acc = b1[i];
        for (int c2 = 0; c2 < SE_C; ++c2) acc = fmaf(srow[c2], wrow[c2], acc);
        h_sh[b][i] = fmaxf(acc, 0.f);
    }
    __syncthreads();

    // g[b][c] = sigmoid(b2[c] + dot(h[b,:], w2[c,:])) ; thread tid owns c=tid
    const int c = tid;
    float wl[SE_HID];
    const float* w2r = w2 + c * SE_HID;
#pragma unroll
    for (int k = 0; k < SE_HID; ++k) wl[k] = w2r[k];
    const float bias = b2[c];
    for (int b = 0; b < SE_B; ++b) {
        float acc = bias;
#pragma unroll
        for (int k = 0; k < SE_HID; ++k) acc = fmaf(h_sh[b][k], wl[k], acc);
        g[b * SE_C + c] = 1.0f / (1.0f + expf(-acc));
    }
}

// Kernel 2: pure stream — out = x * g[plane]. One block per plane; g lookup
// is block-uniform. NT stores keep out from evicting x's L3 lines.
__global__ __launch_bounds__(256) void se_scale_kernel(const float* __restrict__ x,
                                                       const float* __restrict__ g,
                                                       float* __restrict__ out) {
    const int plane = blockIdx.x;
    const int tid = threadIdx.x;
    const float gv = g[plane];
    const float4* xp = (const float4*)x + (size_t)plane * SE_HW4;
    float4* op = (float4*)out + (size_t)plane * SE_HW4;
#pragma unroll
    for (int k = 0; k < 4; ++k) {
        float4 v = xp[tid + k * 256];
        v.x *= gv; v.y *= gv; v.z *= gv; v.w *= gv;
        __builtin_nontemporal_store(*(f4v*)&v, (f4v*)(op + tid + k * 256));
    }
}

extern "C" void kernel_launch(void* const* d_in, const int* in_sizes, int n_in,
                              void* d_out, int out_size, void* d_ws, size_t ws_size,
                              hipStream_t stream) {
    const float* x  = (const float*)d_in[0];
    const float* w1 = (const float*)d_in[1];
    const float* b1 = (const float*)d_in[2];
    const float* w2 = (const float*)d_in[3];
    const float* b2 = (const float*)d_in[4];
    float* out = (float*)d_out;

    unsigned int* counter = (unsigned int*)d_ws;
    float* s = (float*)d_ws + 16;          // [B*C] plane means
    float* g = s + SE_PLANES;              // [B*C] gates

    se_init_kernel<<<1, 1, 0, stream>>>(counter);
    se_mean_gate_kernel<<<SE_PLANES, 256, 0, stream>>>(x, w1, b1, w2, b2, s, g, counter);
    se_scale_kernel<<<SE_PLANES, 256, 0, stream>>>(x, g, out);
}

// Round 4
// 277.190 us; speedup vs baseline: 2.1667x; 2.1667x over previous
//
#include <hip/hip_runtime.h>
#include <math.h>

#define SE_B   32
#define SE_C   256
#define SE_HID 16
#define SE_HW  4096   // 64*64
#define SE_HW4 1024   // float4 per (b,c) plane
#define SE_PLANES (SE_B * SE_C)

typedef float f4v __attribute__((ext_vector_type(4)));

// Kernel 1: plane means, one WAVE per plane (no LDS, no __syncthreads).
// Block = 256 threads = 4 waves = 4 planes; grid = 2048 blocks.
// Lane l of wave w reads float4s [l, l+64, ..., l+15*64] of its plane.
__global__ __launch_bounds__(256) void se_mean_kernel(const float* __restrict__ x,
                                                      float* __restrict__ s) {
    const int wave = threadIdx.x >> 6;                 // 0..3
    const int lane = threadIdx.x & 63;
    const int plane = blockIdx.x * 4 + wave;           // b*C + c
    const float4* xp = (const float4*)x + (size_t)plane * SE_HW4;

    float sum = 0.f;
#pragma unroll
    for (int k = 0; k < 16; ++k) {
        float4 v = xp[lane + k * 64];
        sum += (v.x + v.y) + (v.z + v.w);
    }
#pragma unroll
    for (int off = 32; off > 0; off >>= 1) sum += __shfl_down(sum, off, 64);
    if (lane == 0) s[plane] = sum * (1.0f / SE_HW);
}

// Kernel 2: tiny MLP, one block of 256 threads computes all B*C gates.
__global__ __launch_bounds__(256) void se_gate_kernel(
    const float* __restrict__ s,
    const float* __restrict__ w1, const float* __restrict__ b1,
    const float* __restrict__ w2, const float* __restrict__ b2,
    float* __restrict__ g) {
    const int tid = threadIdx.x;

    // h[b][i] = relu(b1[i] + dot(s[b,:], w1[i,:])); 512 values, 2 rounds
    __shared__ float h_sh[SE_B][SE_HID];  // 2 KB
#pragma unroll
    for (int rb = 0; rb < 2; ++rb) {
        const int b = rb * 16 + (tid >> 4);
        const int i = tid & 15;
        const float* srow = s + b * SE_C;
        const float* wrow = w1 + i * SE_C;
        float acc = b1[i];
        for (int c2 = 0; c2 < SE_C; ++c2) acc = fmaf(srow[c2], wrow[c2], acc);
        h_sh[b][i] = fmaxf(acc, 0.f);
    }
    __syncthreads();

    // g[b][c] = sigmoid(b2[c] + dot(h[b,:], w2[c,:])); thread owns c=tid
    const int c = tid;
    float wl[SE_HID];
    const float* w2r = w2 + c * SE_HID;
#pragma unroll
    for (int k = 0; k < SE_HID; ++k) wl[k] = w2r[k];
    const float bias = b2[c];
    for (int b = 0; b < SE_B; ++b) {
        float acc = bias;
#pragma unroll
        for (int k = 0; k < SE_HID; ++k) acc = fmaf(h_sh[b][k], wl[k], acc);
        g[b * SE_C + c] = 1.0f / (1.0f + expf(-acc));
    }
}

// Kernel 3: pure stream — out = x * g[plane]; g lookup is block-uniform.
__global__ __launch_bounds__(256) void se_scale_kernel(const float* __restrict__ x,
                                                       const float* __restrict__ g,
                                                       float* __restrict__ out) {
    const int plane = blockIdx.x;
    const int tid = threadIdx.x;
    const float gv = g[plane];
    const float4* xp = (const float4*)x + (size_t)plane * SE_HW4;
    float4* op = (float4*)out + (size_t)plane * SE_HW4;
#pragma unroll
    for (int k = 0; k < 4; ++k) {
        float4 v = xp[tid + k * 256];
        v.x *= gv; v.y *= gv; v.z *= gv; v.w *= gv;
        __builtin_nontemporal_store(*(f4v*)&v, (f4v*)(op + tid + k * 256));
    }
}

extern "C" void kernel_launch(void* const* d_in, const int* in_sizes, int n_in,
                              void* d_out, int out_size, void* d_ws, size_t ws_size,
                              hipStream_t stream) {
    const float* x  = (const float*)d_in[0];
    const float* w1 = (const float*)d_in[1];
    const float* b1 = (const float*)d_in[2];
    const float* w2 = (const float*)d_in[3];
    const float* b2 = (const float*)d_in[4];
    float* out = (float*)d_out;

    float* s = (float*)d_ws;        // [B*C] plane means
    float* g = s + SE_PLANES;       // [B*C] gates

    se_mean_kernel<<<SE_PLANES / 4, 256, 0, stream>>>(x, s);
    se_gate_kernel<<<1, 256, 0, stream>>>(s, w1, b1, w2, b2, g);
    se_scale_kernel<<<SE_PLANES, 256, 0, stream>>>(x, g, out);
}